// Round 8
// baseline (2271.225 us; speedup 1.0000x reference)
//
#include <hip/hip_runtime.h>
#include <cstdint>
#include <cstddef>

#define NTOK 4096      // H*W
#define HD 64          // head dim
#define CDIM 512       // channels
#define NPAIRS 64      // B * num_heads
#define K1_SPLIT 32    // blocks per pair in K1
#define K1_TOKENS 128  // tokens per K1 block
#define EPS_F 1e-6f
#define EPS_LN 1e-5f
#define ATT_SCALE 0.125
#define PAD 68         // fp32 LDS row pad: 272B rows, 16B-aligned

__device__ __forceinline__ float elu_eps(float y) {
    return (y > 0.f ? y : (__expf(y) - 1.f)) + EPS_F;
}

// 16-wide feature-map accumulation step (proven fast in K2 since round 5)
#define FEAT_DB_STEP(src)                                                         \
    {                                                                             \
        float kr[16];                                                             \
        _Pragma("unroll")                                                         \
        for (int r = 0; r < 16; ++r)                                              \
            kr[r] = src[(size_t)(16 * db + r) * NTOK + n0 + fn];                  \
        _Pragma("unroll")                                                         \
        for (int j = 0; j < 16; ++j) {                                            \
            const float* wr = fm_w + (size_t)(e0f + j) * 64 + 16 * db;            \
            const float4 w0 = *(const float4*)(wr + 0);                           \
            const float4 w1 = *(const float4*)(wr + 4);                           \
            const float4 w2 = *(const float4*)(wr + 8);                           \
            const float4 w3 = *(const float4*)(wr + 12);                          \
            float t = a16[j];                                                     \
            t = fmaf(kr[0],  w0.x, t); t = fmaf(kr[1],  w0.y, t);                 \
            t = fmaf(kr[2],  w0.z, t); t = fmaf(kr[3],  w0.w, t);                 \
            t = fmaf(kr[4],  w1.x, t); t = fmaf(kr[5],  w1.y, t);                 \
            t = fmaf(kr[6],  w1.z, t); t = fmaf(kr[7],  w1.w, t);                 \
            t = fmaf(kr[8],  w2.x, t); t = fmaf(kr[9],  w2.y, t);                 \
            t = fmaf(kr[10], w2.z, t); t = fmaf(kr[11], w2.w, t);                 \
            t = fmaf(kr[12], w3.x, t); t = fmaf(kr[13], w3.y, t);                 \
            t = fmaf(kr[14], w3.z, t); t = fmaf(kr[15], w3.w, t);                 \
            a16[j] = t;                                                           \
        }                                                                         \
    }

// ---------------------------------------------------------------------------
// K1: per (pair, split) partials, NO atomics (deterministic):
//   kv_part[split][pair][d][e] = sum_n kf[n][d] v[n][e]   (unscaled)
//   ks_part[split][pair][d]    = sum_n kf[n][d]
// PHASE-DISJOINT structure (the r5/r6/r7 spills came from acc[8][8] being
// live across the load-heavy feature phase):
//   Phase A: feature map for all 128 tokens -> LDS kf; stage V^T -> LDS.
//   Phase B: acc[8][8] born here; pure-LDS broadcast GEMM.
//   Phase C: cross-wave reduce + store.
// ---------------------------------------------------------------------------
__global__ __launch_bounds__(256, 3) void k_kvsum(const float* __restrict__ kin,
                                                  const float* __restrict__ vin,
                                                  const float* __restrict__ fm_w,
                                                  const float* __restrict__ fm_b,
                                                  float* __restrict__ kv_part,
                                                  float* __restrict__ ks_part)
{
    __shared__ float vtT[K1_TOKENS][PAD];   // [n][e] transposed V
    __shared__ float kf[K1_TOKENS][PAD];    // [n][d_f]; rows 0..63 reused as Red

    const int tid  = threadIdx.x;
    const int lane = tid & 63;
    const int wv   = tid >> 6;

    const int pair  = blockIdx.x >> 5;
    const int split = blockIdx.x & (K1_SPLIT - 1);
    const int bb = pair >> 3, hh = pair & 7;
    const float* kb = kin + (size_t)(bb * CDIM + hh * HD) * NTOK;
    const float* vb = vin + (size_t)(bb * CDIM + hh * HD) * NTOK;

    const int fn  = lane;              // feature token (within 64-chunk)
    const int e0f = wv * 16;           // feature e-range (wave-owned)
    const int d0  = (lane >> 3) * 8;   // kv tile rows
    const int e0  = (lane & 7) * 8;    // kv tile cols
    const int snn = (tid >> 4) * 4;    // staging token quad
    const int se0 = (tid & 15) * 4;    // staging e quad

    float bias[16];
    #pragma unroll
    for (int j = 0; j < 16; ++j) bias[j] = fm_b[e0f + j];
    float ksp[16];
    #pragma unroll
    for (int j = 0; j < 16; ++j) ksp[j] = 0.f;

    // ================= Phase A: feature + V staging (no acc live) ==========
    #pragma unroll 1
    for (int c = 0; c < 2; ++c) {
        const int n0 = split * K1_TOKENS + c * 64;
        // ---- stage V transposed: 4x4 register transpose, float4 LDS writes ----
        {
            float4 vx0 = *(const float4*)(vb + (size_t)(se0 + 0) * NTOK + n0 + snn);
            float4 vx1 = *(const float4*)(vb + (size_t)(se0 + 1) * NTOK + n0 + snn);
            float4 vx2 = *(const float4*)(vb + (size_t)(se0 + 2) * NTOK + n0 + snn);
            float4 vx3 = *(const float4*)(vb + (size_t)(se0 + 3) * NTOK + n0 + snn);
            *(float4*)&vtT[c * 64 + snn + 0][se0] = make_float4(vx0.x, vx1.x, vx2.x, vx3.x);
            *(float4*)&vtT[c * 64 + snn + 1][se0] = make_float4(vx0.y, vx1.y, vx2.y, vx3.y);
            *(float4*)&vtT[c * 64 + snn + 2][se0] = make_float4(vx0.z, vx1.z, vx2.z, vx3.z);
            *(float4*)&vtT[c * 64 + snn + 3][se0] = make_float4(vx0.w, vx1.w, vx2.w, vx3.w);
        }
        // ---- feature map for token fn (K direct from global) ----
        {
            float a16[16];
            #pragma unroll
            for (int j = 0; j < 16; ++j) a16[j] = bias[j];
            #pragma unroll
            for (int db = 0; db < 4; ++db) FEAT_DB_STEP(kb)
            #pragma unroll
            for (int j = 0; j < 16; ++j) {
                a16[j] = elu_eps(a16[j]);
                ksp[j] += a16[j];
            }
            #pragma unroll
            for (int i = 0; i < 4; ++i)
                *(float4*)&kf[c * 64 + fn][e0f + 4 * i] =
                    make_float4(a16[4 * i], a16[4 * i + 1], a16[4 * i + 2], a16[4 * i + 3]);
        }
    }
    __syncthreads();

    // ================= Phase B: kv GEMM (acc born here) ====================
    float acc[8][8];
    #pragma unroll
    for (int i = 0; i < 8; ++i)
        #pragma unroll
        for (int j = 0; j < 8; ++j) acc[i][j] = 0.f;

    #pragma unroll 4
    for (int tt = 0; tt < 32; ++tt) {
        const int n = 32 * wv + tt;   // wave-uniform -> broadcast LDS reads
        const float4 a0_ = *(const float4*)&kf[n][d0];
        const float4 a1_ = *(const float4*)&kf[n][d0 + 4];
        const float4 b0_ = *(const float4*)&vtT[n][e0];
        const float4 b1_ = *(const float4*)&vtT[n][e0 + 4];
        const float av[8] = {a0_.x, a0_.y, a0_.z, a0_.w, a1_.x, a1_.y, a1_.z, a1_.w};
        const float bv[8] = {b0_.x, b0_.y, b0_.z, b0_.w, b1_.x, b1_.y, b1_.z, b1_.w};
        #pragma unroll
        for (int i = 0; i < 8; ++i)
            #pragma unroll
            for (int j = 0; j < 8; ++j)
                acc[i][j] = fmaf(av[i], bv[j], acc[i][j]);
    }

    // ---- ksum: wave shuffle-reduce over tokens; lane 0 stores (no atomic) ----
    #pragma unroll
    for (int j = 0; j < 16; ++j) {
        float v = ksp[j];
        v += __shfl_xor(v, 1, 64);
        v += __shfl_xor(v, 2, 64);
        v += __shfl_xor(v, 4, 64);
        v += __shfl_xor(v, 8, 64);
        v += __shfl_xor(v, 16, 64);
        v += __shfl_xor(v, 32, 64);
        if (lane == 0)
            ks_part[((size_t)split * NPAIRS + pair) * HD + e0f + j] = v;
    }

    // ================= Phase C: cross-wave reduce + store ==================
    __syncthreads();   // all kf/vtT reads done; safe to overwrite kf as Red
    for (int w = 0; w < 4; ++w) {
        if (wv == w) {
            #pragma unroll
            for (int i = 0; i < 8; ++i) {
                if (w == 0) {
                    *(float4*)&kf[d0 + i][e0]     = make_float4(acc[i][0], acc[i][1], acc[i][2], acc[i][3]);
                    *(float4*)&kf[d0 + i][e0 + 4] = make_float4(acc[i][4], acc[i][5], acc[i][6], acc[i][7]);
                } else {
                    float4 r0 = *(const float4*)&kf[d0 + i][e0];
                    float4 r1 = *(const float4*)&kf[d0 + i][e0 + 4];
                    r0.x += acc[i][0]; r0.y += acc[i][1]; r0.z += acc[i][2]; r0.w += acc[i][3];
                    r1.x += acc[i][4]; r1.y += acc[i][5]; r1.z += acc[i][6]; r1.w += acc[i][7];
                    *(float4*)&kf[d0 + i][e0]     = r0;
                    *(float4*)&kf[d0 + i][e0 + 4] = r1;
                }
            }
        }
        __syncthreads();
    }
    {
        float* kvp = kv_part + ((size_t)split * NPAIRS + pair) * (HD * HD);
        const int r0 = (tid >> 4) * 4;
        const int c0 = (tid & 15) * 4;
        #pragma unroll
        for (int i = 0; i < 4; ++i)
            *(float4*)(kvp + (size_t)(r0 + i) * HD + c0) = *(const float4*)&kf[r0 + i][c0];
    }
}

// ---------------------------------------------------------------------------
// K1b: deterministic fixed-order fp64 reduce of the 32 split partials.
// ---------------------------------------------------------------------------
__global__ __launch_bounds__(256) void k_reduce(const float* __restrict__ kv_part,
                                                const float* __restrict__ ks_part,
                                                float* __restrict__ kv_g,
                                                float* __restrict__ ksum_g)
{
    const int pair = blockIdx.x >> 2;
    const int qtr  = blockIdx.x & 3;
    const int tid  = threadIdx.x;

    #pragma unroll
    for (int i = 0; i < 4; ++i) {
        const int idx = qtr * 1024 + i * 256 + tid;
        double s = 0.0;
        for (int sp = 0; sp < K1_SPLIT; ++sp)
            s += (double)kv_part[((size_t)sp * NPAIRS + pair) * (HD * HD) + idx];
        kv_g[(size_t)pair * (HD * HD) + idx] = (float)(s * ATT_SCALE);
    }
    if (qtr == 0 && tid < HD) {
        double s = 0.0;
        for (int sp = 0; sp < K1_SPLIT; ++sp)
            s += (double)ks_part[((size_t)sp * NPAIRS + pair) * HD + tid];
        ksum_g[(size_t)pair * HD + tid] = (float)s;
    }
}

// ---------------------------------------------------------------------------
// K2: out[n][e] = (qf[n]·kv[:,e]) / (qf[n]·ksum + eps).
// fp32 GEMMs; normalizer dot in fp64 (cancellation-critical). Verbatim r7.
// ---------------------------------------------------------------------------
__global__ __launch_bounds__(256, 3) void k_qout(const float* __restrict__ qin,
                                                 const float* __restrict__ fm_w,
                                                 const float* __restrict__ fm_b,
                                                 const float* __restrict__ kv_g,
                                                 const float* __restrict__ ksum_g,
                                                 float* __restrict__ outp)
{
    __shared__ float kvs[64][PAD];    // [d][e]
    __shared__ float qfT[64][PAD];    // [d_f][n]; reused as RedT after out phase
    __shared__ double nred[4][64];    // fp64 normalizer partials
    __shared__ double norm_lds[64];

    const int tid  = threadIdx.x;
    const int lane = tid & 63;
    const int wv   = tid >> 6;

    const int pair  = blockIdx.x >> 6;
    const int chunk = blockIdx.x & 63;
    const int n0    = chunk * 64;
    const int bb = pair >> 3, hh = pair & 7;
    const float* qb = qin + (size_t)(bb * CDIM + hh * HD) * NTOK;

    // ---- stage kv tile ----
    {
        const float* kvg = kv_g + (size_t)pair * (HD * HD);
        const int d  = tid >> 2;
        const int eb = (tid & 3) * 16;
        #pragma unroll
        for (int i = 0; i < 4; ++i)
            *(float4*)&kvs[d][eb + 4 * i] = *(const float4*)(kvg + (size_t)d * 64 + eb + 4 * i);
    }

    const int fn  = lane;
    const int e0f = wv * 16;
    float bias[16], ksr[16];
    #pragma unroll
    for (int j = 0; j < 16; ++j) {
        bias[j] = fm_b[e0f + j];
        ksr[j]  = ksum_g[(size_t)pair * HD + e0f + j];
    }

    // ---- feature map (Q direct from global) -> qfT + fp64 normalizer partial ----
    {
        float a16[16];
        #pragma unroll
        for (int j = 0; j < 16; ++j) a16[j] = bias[j];
        #pragma unroll
        for (int db = 0; db < 4; ++db) FEAT_DB_STEP(qb)
        double np = 0.0;
        #pragma unroll
        for (int j = 0; j < 16; ++j) {
            const float v = elu_eps(a16[j]);
            np += (double)v * (double)ksr[j];
            qfT[e0f + j][fn] = v;
        }
        nred[wv][fn] = np;
    }
    __syncthreads();
    if (tid < 64)
        norm_lds[tid] = nred[0][tid] + nred[1][tid] + nred[2][tid] + nred[3][tid] + (double)EPS_F;
    __syncthreads();

    // ---- out GEMM (transposed acc): wave wv owns d in [16wv, 16wv+16) ----
    const int ea0 = (lane >> 3) * 8;
    const int na0 = (lane & 7) * 8;
    float acc[8][8];
    #pragma unroll
    for (int i = 0; i < 8; ++i)
        #pragma unroll
        for (int j = 0; j < 8; ++j) acc[i][j] = 0.f;
    #pragma unroll
    for (int dd = 0; dd < 16; ++dd) {
        const int d = 16 * wv + dd;   // wave-uniform
        const float4 a0_ = *(const float4*)&kvs[d][ea0];
        const float4 a1_ = *(const float4*)&kvs[d][ea0 + 4];
        const float4 b0_ = *(const float4*)&qfT[d][na0];
        const float4 b1_ = *(const float4*)&qfT[d][na0 + 4];
        const float av[8] = {a0_.x, a0_.y, a0_.z, a0_.w, a1_.x, a1_.y, a1_.z, a1_.w};
        const float bv[8] = {b0_.x, b0_.y, b0_.z, b0_.w, b1_.x, b1_.y, b1_.z, b1_.w};
        #pragma unroll
        for (int i = 0; i < 8; ++i)
            #pragma unroll
            for (int j = 0; j < 8; ++j)
                acc[i][j] = fmaf(av[i], bv[j], acc[i][j]);
    }
    __syncthreads();   // all qfT reads done; safe to overwrite as RedT

    for (int w = 0; w < 4; ++w) {
        if (wv == w) {
            #pragma unroll
            for (int i = 0; i < 8; ++i) {
                if (w == 0) {
                    *(float4*)&qfT[ea0 + i][na0]     = make_float4(acc[i][0], acc[i][1], acc[i][2], acc[i][3]);
                    *(float4*)&qfT[ea0 + i][na0 + 4] = make_float4(acc[i][4], acc[i][5], acc[i][6], acc[i][7]);
                } else {
                    float4 r0 = *(const float4*)&qfT[ea0 + i][na0];
                    float4 r1 = *(const float4*)&qfT[ea0 + i][na0 + 4];
                    r0.x += acc[i][0]; r0.y += acc[i][1]; r0.z += acc[i][2]; r0.w += acc[i][3];
                    r1.x += acc[i][4]; r1.y += acc[i][5]; r1.z += acc[i][6]; r1.w += acc[i][7];
                    *(float4*)&qfT[ea0 + i][na0]     = r0;
                    *(float4*)&qfT[ea0 + i][na0 + 4] = r1;
                }
            }
        }
        __syncthreads();
    }

    // ---- epilogue: divide by fp64 normalizer, coalesced store ----
    {
        const int er0 = (tid >> 4) * 4;   // e rows
        const int nc0 = (tid & 15) * 4;   // n cols
        double rn[4];
        #pragma unroll
        for (int j = 0; j < 4; ++j) rn[j] = 1.0 / norm_lds[nc0 + j];
        float* ob = outp + (size_t)(bb * CDIM + hh * HD) * NTOK + n0;
        #pragma unroll
        for (int i = 0; i < 4; ++i) {
            float4 vv = *(const float4*)&qfT[er0 + i][nc0];
            vv.x = (float)((double)vv.x * rn[0]);
            vv.y = (float)((double)vv.y * rn[1]);
            vv.z = (float)((double)vv.z * rn[2]);
            vv.w = (float)((double)vv.w * rn[3]);
            *(float4*)(ob + (size_t)(er0 + i) * NTOK + nc0) = vv;
        }
    }
}

// ---------------------------------------------------------------------------
// K3: in-place LayerNorm over C, 16 tokens/block, two-pass variance
// ---------------------------------------------------------------------------
__global__ __launch_bounds__(256) void k_layernorm(float* __restrict__ io,
                                                   const float* __restrict__ ln_w,
                                                   const float* __restrict__ ln_b)
{
    __shared__ float xs[512][17];
    __shared__ float mu_s[16];
    __shared__ float rs_s[16];

    const int tid = threadIdx.x;
    const int bb = blockIdx.x >> 8;
    const int chunk = blockIdx.x & 255;
    const int n0 = chunk * 16;
    float* base = io + (size_t)bb * CDIM * NTOK + n0;

    #pragma unroll
    for (int i = 0; i < 8; ++i) {
        const int idx = tid + i * 256;
        const int c = idx >> 2;
        const int f4 = (idx & 3) * 4;
        const float4 vx = *(const float4*)(base + (size_t)c * NTOK + f4);
        xs[c][f4 + 0] = vx.x; xs[c][f4 + 1] = vx.y;
        xs[c][f4 + 2] = vx.z; xs[c][f4 + 3] = vx.w;
    }
    __syncthreads();

    const int n = tid >> 4;
    const int p = tid & 15;
    float s = 0.f;
    #pragma unroll 8
    for (int ci = 0; ci < 32; ++ci) {
        const int c = p * 32 + ((ci + 2 * p) & 31);
        s += xs[c][n];
    }
    s += __shfl_xor(s, 1, 64);
    s += __shfl_xor(s, 2, 64);
    s += __shfl_xor(s, 4, 64);
    s += __shfl_xor(s, 8, 64);
    if (p == 0) mu_s[n] = s * (1.f / 512.f);
    __syncthreads();
    const float mu = mu_s[n];
    float s2 = 0.f;
    #pragma unroll 8
    for (int ci = 0; ci < 32; ++ci) {
        const int c = p * 32 + ((ci + 2 * p) & 31);
        const float x = xs[c][n] - mu;
        s2 = fmaf(x, x, s2);
    }
    s2 += __shfl_xor(s2, 1, 64);
    s2 += __shfl_xor(s2, 2, 64);
    s2 += __shfl_xor(s2, 4, 64);
    s2 += __shfl_xor(s2, 8, 64);
    if (p == 0) rs_s[n] = rsqrtf(s2 * (1.f / 512.f) + EPS_LN);
    __syncthreads();

    #pragma unroll
    for (int i = 0; i < 8; ++i) {
        const int idx = tid + i * 256;
        const int c = idx >> 2;
        const int f4 = (idx & 3) * 4;
        const float w = ln_w[c];
        const float b2 = ln_b[c];
        float4 ov;
        ov.x = (xs[c][f4 + 0] - mu_s[f4 + 0]) * rs_s[f4 + 0] * w + b2;
        ov.y = (xs[c][f4 + 1] - mu_s[f4 + 1]) * rs_s[f4 + 1] * w + b2;
        ov.z = (xs[c][f4 + 2] - mu_s[f4 + 2]) * rs_s[f4 + 2] * w + b2;
        ov.w = (xs[c][f4 + 3] - mu_s[f4 + 3]) * rs_s[f4 + 3] * w + b2;
        *(float4*)(base + (size_t)c * NTOK + f4) = ov;
    }
}

// ---------------------------------------------------------------------------
extern "C" void kernel_launch(void* const* d_in, const int* in_sizes, int n_in,
                              void* d_out, int out_size, void* d_ws, size_t ws_size,
                              hipStream_t stream) {
    (void)in_sizes; (void)n_in; (void)out_size; (void)ws_size;
    const float* q    = (const float*)d_in[0];
    const float* k    = (const float*)d_in[1];
    const float* v    = (const float*)d_in[2];
    const float* fm_w = (const float*)d_in[3];
    const float* fm_b = (const float*)d_in[4];
    const float* ln_w = (const float*)d_in[5];
    const float* ln_b = (const float*)d_in[6];
    float* out = (float*)d_out;

    // ws layout (all regions fully written before read; no memset needed):
    float* kv_part = (float*)d_ws;                                       // 32*64*4096 floats
    float* ks_part = kv_part + (size_t)K1_SPLIT * NPAIRS * HD * HD;      // 32*64*64
    float* kv_g    = ks_part + (size_t)K1_SPLIT * NPAIRS * HD;           // 64*4096
    float* ksum_g  = kv_g + (size_t)NPAIRS * HD * HD;                    // 64*64

    k_kvsum<<<NPAIRS * K1_SPLIT, 256, 0, stream>>>(k, v, fm_w, fm_b, kv_part, ks_part);
    k_reduce<<<NPAIRS * 4, 256, 0, stream>>>(kv_part, ks_part, kv_g, ksum_g);
    k_qout<<<NPAIRS * (NTOK / 64), 256, 0, stream>>>(q, fm_w, fm_b, kv_g, ksum_g, out);
    k_layernorm<<<8 * (NTOK / 16), 256, 0, stream>>>(out, ln_w, ln_b);
}

// Round 9
// 547.917 us; speedup vs baseline: 4.1452x; 4.1452x over previous
//
#include <hip/hip_runtime.h>
#include <cstdint>
#include <cstddef>

#define NTOK 4096      // H*W
#define HD 64          // head dim
#define CDIM 512       // channels
#define NPAIRS 64      // B * num_heads
#define K1B_SPLIT 16   // kv partial splits (256 tokens each)
#define EPS_F 1e-6f
#define EPS_LN 1e-5f
#define ATT_SCALE 0.125
#define PAD 68         // fp32 LDS row pad: 272B rows, 16B-aligned

__device__ __forceinline__ float elu_eps(float y) {
    return (y > 0.f ? y : (__expf(y) - 1.f)) + EPS_F;
}

// 16-wide feature-map accumulation step (proven fast in K2 since round 5)
#define FEAT_DB_STEP(src)                                                         \
    {                                                                             \
        float kr[16];                                                             \
        _Pragma("unroll")                                                         \
        for (int r = 0; r < 16; ++r)                                              \
            kr[r] = src[(size_t)(16 * db + r) * NTOK + n0 + fn];                  \
        _Pragma("unroll")                                                         \
        for (int j = 0; j < 16; ++j) {                                            \
            const float* wr = fm_w + (size_t)(e0f + j) * 64 + 16 * db;            \
            const float4 w0 = *(const float4*)(wr + 0);                           \
            const float4 w1 = *(const float4*)(wr + 4);                           \
            const float4 w2 = *(const float4*)(wr + 8);                           \
            const float4 w3 = *(const float4*)(wr + 12);                          \
            float t = a16[j];                                                     \
            t = fmaf(kr[0],  w0.x, t); t = fmaf(kr[1],  w0.y, t);                 \
            t = fmaf(kr[2],  w0.z, t); t = fmaf(kr[3],  w0.w, t);                 \
            t = fmaf(kr[4],  w1.x, t); t = fmaf(kr[5],  w1.y, t);                 \
            t = fmaf(kr[6],  w1.z, t); t = fmaf(kr[7],  w1.w, t);                 \
            t = fmaf(kr[8],  w2.x, t); t = fmaf(kr[9],  w2.y, t);                 \
            t = fmaf(kr[10], w2.z, t); t = fmaf(kr[11], w2.w, t);                 \
            t = fmaf(kr[12], w3.x, t); t = fmaf(kr[13], w3.y, t);                 \
            t = fmaf(kr[14], w3.z, t); t = fmaf(kr[15], w3.w, t);                 \
            a16[j] = t;                                                           \
        }                                                                         \
    }

// ---------------------------------------------------------------------------
// K1a: feature map over K only (no LDS, no accumulator — K2's proven regime).
//   kf_ws[pair][d][n] = elu(K W^T + b)+eps   (transposed store, coalesced)
//   ks_part[chunk][pair][d] = sum over this block's 64 tokens
// ---------------------------------------------------------------------------
__global__ __launch_bounds__(256, 4) void k_feat_k(const float* __restrict__ kin,
                                                   const float* __restrict__ fm_w,
                                                   const float* __restrict__ fm_b,
                                                   float* __restrict__ kf_ws,
                                                   float* __restrict__ ks_part)
{
    const int tid  = threadIdx.x;
    const int lane = tid & 63;
    const int wv   = tid >> 6;

    const int pair  = blockIdx.x >> 6;
    const int chunk = blockIdx.x & 63;
    const int n0    = chunk * 64;
    const int bb = pair >> 3, hh = pair & 7;
    const float* kb = kin + (size_t)(bb * CDIM + hh * HD) * NTOK;

    const int fn  = lane;
    const int e0f = wv * 16;

    float a16[16];
    #pragma unroll
    for (int j = 0; j < 16; ++j) a16[j] = fm_b[e0f + j];
    #pragma unroll
    for (int db = 0; db < 4; ++db) FEAT_DB_STEP(kb)

    #pragma unroll
    for (int j = 0; j < 16; ++j) a16[j] = elu_eps(a16[j]);

    // transposed store: per j, lanes write 64 consecutive n -> 256B coalesced
    float* kfb = kf_ws + (size_t)pair * HD * NTOK;
    #pragma unroll
    for (int j = 0; j < 16; ++j)
        kfb[(size_t)(e0f + j) * NTOK + n0 + fn] = a16[j];

    // ksum chunk-partials (shuffle reduce; deterministic, no atomics)
    #pragma unroll
    for (int j = 0; j < 16; ++j) {
        float v = a16[j];
        v += __shfl_xor(v, 1, 64);
        v += __shfl_xor(v, 2, 64);
        v += __shfl_xor(v, 4, 64);
        v += __shfl_xor(v, 8, 64);
        v += __shfl_xor(v, 16, 64);
        v += __shfl_xor(v, 32, 64);
        if (lane == 0)
            ks_part[((size_t)chunk * NPAIRS + pair) * HD + e0f + j] = v;
    }
}

// ---------------------------------------------------------------------------
// K1b: pure GEMM  kv_part[split][pair][d][e] = sum_{n in split} kf[n][d] v[n][e]
// Stage kf/V chunks via 4x4 register transpose (r4-proven), broadcast 8x8 GEMM.
// Only ~30 staging floats live alongside acc[8][8] -> no spill.
// ---------------------------------------------------------------------------
__global__ __launch_bounds__(256, 3) void k_kv(const float* __restrict__ vin,
                                               const float* __restrict__ kf_ws,
                                               float* __restrict__ kv_part)
{
    __shared__ float kf_l[64][PAD];   // [n][d]
    __shared__ float vtT[64][PAD];    // [n][e]

    const int tid  = threadIdx.x;
    const int lane = tid & 63;
    const int wv   = tid >> 6;

    const int pair  = blockIdx.x >> 4;
    const int split = blockIdx.x & (K1B_SPLIT - 1);
    const int bb = pair >> 3, hh = pair & 7;
    const float* vb  = vin + (size_t)(bb * CDIM + hh * HD) * NTOK;
    const float* kfb = kf_ws + (size_t)pair * HD * NTOK;

    const int dq = (tid >> 4) * 4;    // staging row quad (d or e)
    const int nq = (tid & 15) * 4;    // staging n quad
    const int d0 = (lane >> 3) * 8;   // GEMM tile rows
    const int e0 = (lane & 7) * 8;    // GEMM tile cols

    float acc[8][8];
    #pragma unroll
    for (int i = 0; i < 8; ++i)
        #pragma unroll
        for (int j = 0; j < 8; ++j) acc[i][j] = 0.f;

    #pragma unroll 1
    for (int c = 0; c < 4; ++c) {
        const int n0 = split * 256 + c * 64;
        __syncthreads();   // previous chunk's GEMM reads done

        // stage kf chunk: rows d=dq+r, 4x4 transpose -> kf_l[n][d]
        {
            float4 x0 = *(const float4*)(kfb + (size_t)(dq + 0) * NTOK + n0 + nq);
            float4 x1 = *(const float4*)(kfb + (size_t)(dq + 1) * NTOK + n0 + nq);
            float4 x2 = *(const float4*)(kfb + (size_t)(dq + 2) * NTOK + n0 + nq);
            float4 x3 = *(const float4*)(kfb + (size_t)(dq + 3) * NTOK + n0 + nq);
            *(float4*)&kf_l[nq + 0][dq] = make_float4(x0.x, x1.x, x2.x, x3.x);
            *(float4*)&kf_l[nq + 1][dq] = make_float4(x0.y, x1.y, x2.y, x3.y);
            *(float4*)&kf_l[nq + 2][dq] = make_float4(x0.z, x1.z, x2.z, x3.z);
            *(float4*)&kf_l[nq + 3][dq] = make_float4(x0.w, x1.w, x2.w, x3.w);
        }
        // stage V chunk: rows e=dq+r, 4x4 transpose -> vtT[n][e]
        {
            float4 x0 = *(const float4*)(vb + (size_t)(dq + 0) * NTOK + n0 + nq);
            float4 x1 = *(const float4*)(vb + (size_t)(dq + 1) * NTOK + n0 + nq);
            float4 x2 = *(const float4*)(vb + (size_t)(dq + 2) * NTOK + n0 + nq);
            float4 x3 = *(const float4*)(vb + (size_t)(dq + 3) * NTOK + n0 + nq);
            *(float4*)&vtT[nq + 0][dq] = make_float4(x0.x, x1.x, x2.x, x3.x);
            *(float4*)&vtT[nq + 1][dq] = make_float4(x0.y, x1.y, x2.y, x3.y);
            *(float4*)&vtT[nq + 2][dq] = make_float4(x0.z, x1.z, x2.z, x3.z);
            *(float4*)&vtT[nq + 3][dq] = make_float4(x0.w, x1.w, x2.w, x3.w);
        }
        __syncthreads();

        // broadcast 8x8 GEMM: wave wv owns tokens [16wv, 16wv+16)
        #pragma unroll 4
        for (int tt = 0; tt < 16; ++tt) {
            const int n = 16 * wv + tt;   // wave-uniform -> broadcast LDS reads
            const float4 a0_ = *(const float4*)&kf_l[n][d0];
            const float4 a1_ = *(const float4*)&kf_l[n][d0 + 4];
            const float4 b0_ = *(const float4*)&vtT[n][e0];
            const float4 b1_ = *(const float4*)&vtT[n][e0 + 4];
            const float av[8] = {a0_.x, a0_.y, a0_.z, a0_.w, a1_.x, a1_.y, a1_.z, a1_.w};
            const float bv[8] = {b0_.x, b0_.y, b0_.z, b0_.w, b1_.x, b1_.y, b1_.z, b1_.w};
            #pragma unroll
            for (int i = 0; i < 8; ++i)
                #pragma unroll
                for (int j = 0; j < 8; ++j)
                    acc[i][j] = fmaf(av[i], bv[j], acc[i][j]);
        }
    }

    // cross-wave reduce (reuse kf_l as Red), then store partial
    __syncthreads();
    for (int w = 0; w < 4; ++w) {
        if (wv == w) {
            #pragma unroll
            for (int i = 0; i < 8; ++i) {
                if (w == 0) {
                    *(float4*)&kf_l[d0 + i][e0]     = make_float4(acc[i][0], acc[i][1], acc[i][2], acc[i][3]);
                    *(float4*)&kf_l[d0 + i][e0 + 4] = make_float4(acc[i][4], acc[i][5], acc[i][6], acc[i][7]);
                } else {
                    float4 r0 = *(const float4*)&kf_l[d0 + i][e0];
                    float4 r1 = *(const float4*)&kf_l[d0 + i][e0 + 4];
                    r0.x += acc[i][0]; r0.y += acc[i][1]; r0.z += acc[i][2]; r0.w += acc[i][3];
                    r1.x += acc[i][4]; r1.y += acc[i][5]; r1.z += acc[i][6]; r1.w += acc[i][7];
                    *(float4*)&kf_l[d0 + i][e0]     = r0;
                    *(float4*)&kf_l[d0 + i][e0 + 4] = r1;
                }
            }
        }
        __syncthreads();
    }
    {
        float* kvp = kv_part + ((size_t)split * NPAIRS + pair) * (HD * HD);
        const int r0 = (tid >> 4) * 4;
        const int c0 = (tid & 15) * 4;
        #pragma unroll
        for (int i = 0; i < 4; ++i)
            *(float4*)(kvp + (size_t)(r0 + i) * HD + c0) = *(const float4*)&kf_l[r0 + i][c0];
    }
}

// ---------------------------------------------------------------------------
// K1c: deterministic fixed-order fp64 reduce of partials.
// ---------------------------------------------------------------------------
__global__ __launch_bounds__(256) void k_reduce(const float* __restrict__ kv_part,
                                                const float* __restrict__ ks_part,
                                                float* __restrict__ kv_g,
                                                float* __restrict__ ksum_g)
{
    const int pair = blockIdx.x >> 2;
    const int qtr  = blockIdx.x & 3;
    const int tid  = threadIdx.x;

    #pragma unroll
    for (int i = 0; i < 4; ++i) {
        const int idx = qtr * 1024 + i * 256 + tid;
        double s = 0.0;
        for (int sp = 0; sp < K1B_SPLIT; ++sp)
            s += (double)kv_part[((size_t)sp * NPAIRS + pair) * (HD * HD) + idx];
        kv_g[(size_t)pair * (HD * HD) + idx] = (float)(s * ATT_SCALE);
    }
    if (qtr == 0 && tid < HD) {
        double s = 0.0;
        for (int c = 0; c < 64; ++c)
            s += (double)ks_part[((size_t)c * NPAIRS + pair) * HD + tid];
        ksum_g[(size_t)pair * HD + tid] = (float)s;
    }
}

// ---------------------------------------------------------------------------
// K2: out[n][e] = (qf[n]·kv[:,e]) / (qf[n]·ksum + eps), fp32
// (verbatim round-5 version: proven correct (absmax 0.03125) and fast)
// ---------------------------------------------------------------------------
__global__ __launch_bounds__(256, 3) void k_qout(const float* __restrict__ qin,
                                                 const float* __restrict__ fm_w,
                                                 const float* __restrict__ fm_b,
                                                 const float* __restrict__ kv_g,
                                                 const float* __restrict__ ksum_g,
                                                 float* __restrict__ outp)
{
    __shared__ float kvs[64][PAD];   // [d][e]
    __shared__ float qfT[64][PAD];   // [d_f][n]; reused as RedT after out phase
    __shared__ float nred[4][64];
    __shared__ float norm_lds[64];

    const int tid  = threadIdx.x;
    const int lane = tid & 63;
    const int wv   = tid >> 6;

    const int pair  = blockIdx.x >> 6;
    const int chunk = blockIdx.x & 63;
    const int n0    = chunk * 64;
    const int bb = pair >> 3, hh = pair & 7;
    const float* qb = qin + (size_t)(bb * CDIM + hh * HD) * NTOK;

    // ---- stage kv tile ----
    {
        const float* kvg = kv_g + (size_t)pair * (HD * HD);
        const int d  = tid >> 2;
        const int eb = (tid & 3) * 16;
        #pragma unroll
        for (int i = 0; i < 4; ++i)
            *(float4*)&kvs[d][eb + 4 * i] = *(const float4*)(kvg + (size_t)d * 64 + eb + 4 * i);
    }

    const int fn  = lane;
    const int e0f = wv * 16;
    float bias[16], ksr[16];
    #pragma unroll
    for (int j = 0; j < 16; ++j) {
        bias[j] = fm_b[e0f + j];
        ksr[j]  = ksum_g[(size_t)pair * HD + e0f + j];
    }

    // ---- feature map (Q direct from global) -> qfT + normalizer partial ----
    {
        float a16[16];
        #pragma unroll
        for (int j = 0; j < 16; ++j) a16[j] = bias[j];
        #pragma unroll
        for (int db = 0; db < 4; ++db) FEAT_DB_STEP(qb)
        float np = 0.f;
        #pragma unroll
        for (int j = 0; j < 16; ++j) {
            const float v = elu_eps(a16[j]);
            np = fmaf(v, ksr[j], np);
            qfT[e0f + j][fn] = v;
        }
        nred[wv][fn] = np;
    }
    __syncthreads();
    if (tid < 64)
        norm_lds[tid] = nred[0][tid] + nred[1][tid] + nred[2][tid] + nred[3][tid] + EPS_F;
    __syncthreads();

    // ---- out GEMM (transposed acc): wave wv owns d in [16wv, 16wv+16) ----
    const int ea0 = (lane >> 3) * 8;
    const int na0 = (lane & 7) * 8;
    float acc[8][8];
    #pragma unroll
    for (int i = 0; i < 8; ++i)
        #pragma unroll
        for (int j = 0; j < 8; ++j) acc[i][j] = 0.f;
    #pragma unroll
    for (int dd = 0; dd < 16; ++dd) {
        const int d = 16 * wv + dd;   // wave-uniform
        const float4 a0_ = *(const float4*)&kvs[d][ea0];
        const float4 a1_ = *(const float4*)&kvs[d][ea0 + 4];
        const float4 b0_ = *(const float4*)&qfT[d][na0];
        const float4 b1_ = *(const float4*)&qfT[d][na0 + 4];
        const float av[8] = {a0_.x, a0_.y, a0_.z, a0_.w, a1_.x, a1_.y, a1_.z, a1_.w};
        const float bv[8] = {b0_.x, b0_.y, b0_.z, b0_.w, b1_.x, b1_.y, b1_.z, b1_.w};
        #pragma unroll
        for (int i = 0; i < 8; ++i)
            #pragma unroll
            for (int j = 0; j < 8; ++j)
                acc[i][j] = fmaf(av[i], bv[j], acc[i][j]);
    }
    __syncthreads();   // all qfT reads done; safe to overwrite as RedT

    for (int w = 0; w < 4; ++w) {
        if (wv == w) {
            #pragma unroll
            for (int i = 0; i < 8; ++i) {
                if (w == 0) {
                    *(float4*)&qfT[ea0 + i][na0]     = make_float4(acc[i][0], acc[i][1], acc[i][2], acc[i][3]);
                    *(float4*)&qfT[ea0 + i][na0 + 4] = make_float4(acc[i][4], acc[i][5], acc[i][6], acc[i][7]);
                } else {
                    float4 r0 = *(const float4*)&qfT[ea0 + i][na0];
                    float4 r1 = *(const float4*)&qfT[ea0 + i][na0 + 4];
                    r0.x += acc[i][0]; r0.y += acc[i][1]; r0.z += acc[i][2]; r0.w += acc[i][3];
                    r1.x += acc[i][4]; r1.y += acc[i][5]; r1.z += acc[i][6]; r1.w += acc[i][7];
                    *(float4*)&qfT[ea0 + i][na0]     = r0;
                    *(float4*)&qfT[ea0 + i][na0 + 4] = r1;
                }
            }
        }
        __syncthreads();
    }

    // ---- epilogue: divide by normalizer, coalesced store ----
    {
        const int er0 = (tid >> 4) * 4;   // e rows
        const int nc0 = (tid & 15) * 4;   // n cols
        float rn[4];
        #pragma unroll
        for (int j = 0; j < 4; ++j) rn[j] = 1.f / norm_lds[nc0 + j];
        float* ob = outp + (size_t)(bb * CDIM + hh * HD) * NTOK + n0;
        #pragma unroll
        for (int i = 0; i < 4; ++i) {
            float4 vv = *(const float4*)&qfT[er0 + i][nc0];
            vv.x *= rn[0]; vv.y *= rn[1]; vv.z *= rn[2]; vv.w *= rn[3];
            *(float4*)(ob + (size_t)(er0 + i) * NTOK + nc0) = vv;
        }
    }
}

// ---------------------------------------------------------------------------
// K3: in-place LayerNorm over C, 16 tokens/block, two-pass variance
// ---------------------------------------------------------------------------
__global__ __launch_bounds__(256) void k_layernorm(float* __restrict__ io,
                                                   const float* __restrict__ ln_w,
                                                   const float* __restrict__ ln_b)
{
    __shared__ float xs[512][17];
    __shared__ float mu_s[16];
    __shared__ float rs_s[16];

    const int tid = threadIdx.x;
    const int bb = blockIdx.x >> 8;
    const int chunk = blockIdx.x & 255;
    const int n0 = chunk * 16;
    float* base = io + (size_t)bb * CDIM * NTOK + n0;

    #pragma unroll
    for (int i = 0; i < 8; ++i) {
        const int idx = tid + i * 256;
        const int c = idx >> 2;
        const int f4 = (idx & 3) * 4;
        const float4 vx = *(const float4*)(base + (size_t)c * NTOK + f4);
        xs[c][f4 + 0] = vx.x; xs[c][f4 + 1] = vx.y;
        xs[c][f4 + 2] = vx.z; xs[c][f4 + 3] = vx.w;
    }
    __syncthreads();

    const int n = tid >> 4;
    const int p = tid & 15;
    float s = 0.f;
    #pragma unroll 8
    for (int ci = 0; ci < 32; ++ci) {
        const int c = p * 32 + ((ci + 2 * p) & 31);
        s += xs[c][n];
    }
    s += __shfl_xor(s, 1, 64);
    s += __shfl_xor(s, 2, 64);
    s += __shfl_xor(s, 4, 64);
    s += __shfl_xor(s, 8, 64);
    if (p == 0) mu_s[n] = s * (1.f / 512.f);
    __syncthreads();
    const float mu = mu_s[n];
    float s2 = 0.f;
    #pragma unroll 8
    for (int ci = 0; ci < 32; ++ci) {
        const int c = p * 32 + ((ci + 2 * p) & 31);
        const float x = xs[c][n] - mu;
        s2 = fmaf(x, x, s2);
    }
    s2 += __shfl_xor(s2, 1, 64);
    s2 += __shfl_xor(s2, 2, 64);
    s2 += __shfl_xor(s2, 4, 64);
    s2 += __shfl_xor(s2, 8, 64);
    if (p == 0) rs_s[n] = rsqrtf(s2 * (1.f / 512.f) + EPS_LN);
    __syncthreads();

    #pragma unroll
    for (int i = 0; i < 8; ++i) {
        const int idx = tid + i * 256;
        const int c = idx >> 2;
        const int f4 = (idx & 3) * 4;
        const float w = ln_w[c];
        const float b2 = ln_b[c];
        float4 ov;
        ov.x = (xs[c][f4 + 0] - mu_s[f4 + 0]) * rs_s[f4 + 0] * w + b2;
        ov.y = (xs[c][f4 + 1] - mu_s[f4 + 1]) * rs_s[f4 + 1] * w + b2;
        ov.z = (xs[c][f4 + 2] - mu_s[f4 + 2]) * rs_s[f4 + 2] * w + b2;
        ov.w = (xs[c][f4 + 3] - mu_s[f4 + 3]) * rs_s[f4 + 3] * w + b2;
        *(float4*)(base + (size_t)c * NTOK + f4) = ov;
    }
}

// ---------------------------------------------------------------------------
extern "C" void kernel_launch(void* const* d_in, const int* in_sizes, int n_in,
                              void* d_out, int out_size, void* d_ws, size_t ws_size,
                              hipStream_t stream) {
    (void)in_sizes; (void)n_in; (void)out_size; (void)ws_size;
    const float* q    = (const float*)d_in[0];
    const float* k    = (const float*)d_in[1];
    const float* v    = (const float*)d_in[2];
    const float* fm_w = (const float*)d_in[3];
    const float* fm_b = (const float*)d_in[4];
    const float* ln_w = (const float*)d_in[5];
    const float* ln_b = (const float*)d_in[6];
    float* out = (float*)d_out;

    // ws layout (all regions fully written before read; no memset needed):
    float* kf_ws   = (float*)d_ws;                                   // 64*64*4096   = 16.78M floats
    float* kv_part = kf_ws   + (size_t)NPAIRS * HD * NTOK;           // 16*64*64*64  =  4.19M
    float* ks_part = kv_part + (size_t)K1B_SPLIT * NPAIRS * HD * HD; // 64*64*64     =  0.26M
    float* kv_g    = ks_part + (size_t)64 * NPAIRS * HD;             // 64*64*64     =  0.26M
    float* ksum_g  = kv_g    + (size_t)NPAIRS * HD * HD;             // 64*64

    k_feat_k<<<NPAIRS * 64, 256, 0, stream>>>(k, fm_w, fm_b, kf_ws, ks_part);
    k_kv<<<NPAIRS * K1B_SPLIT, 256, 0, stream>>>(v, kf_ws, kv_part);
    k_reduce<<<NPAIRS * 4, 256, 0, stream>>>(kv_part, ks_part, kv_g, ksum_g);
    k_qout<<<NPAIRS * (NTOK / 64), 256, 0, stream>>>(q, fm_w, fm_b, kv_g, ksum_g, out);
    k_layernorm<<<8 * (NTOK / 16), 256, 0, stream>>>(out, ln_w, ln_b);
}

// Round 10
// 424.762 us; speedup vs baseline: 5.3471x; 1.2899x over previous
//
#include <hip/hip_runtime.h>
#include <cstdint>
#include <cstddef>

#define NTOK 4096      // H*W
#define HD 64          // head dim
#define CDIM 512       // channels
#define NPAIRS 64      // B * num_heads
#define K1B_SPLIT 16   // kv partial splits (256 tokens each)
#define EPS_F 1e-6f
#define EPS_LN 1e-5f
#define ATT_SCALE 0.125
#define PAD 68         // fp32 LDS row pad: 272B rows, 16B-aligned
#define FPAD 72        // k_feat_k LDS pad: 288B rows, 16B-aligned, 4-way max on readout

__device__ __forceinline__ float elu_eps(float y) {
    return (y > 0.f ? y : (__expf(y) - 1.f)) + EPS_F;
}

// 16-wide feature-map accumulation step (proven fast in K2 since round 5)
#define FEAT_DB_STEP(src)                                                         \
    {                                                                             \
        float kr[16];                                                             \
        _Pragma("unroll")                                                         \
        for (int r = 0; r < 16; ++r)                                              \
            kr[r] = src[(size_t)(16 * db + r) * NTOK + n0 + fn];                  \
        _Pragma("unroll")                                                         \
        for (int j = 0; j < 16; ++j) {                                            \
            const float* wr = fm_w + (size_t)(e0f + j) * 64 + 16 * db;            \
            const float4 w0 = *(const float4*)(wr + 0);                           \
            const float4 w1 = *(const float4*)(wr + 4);                           \
            const float4 w2 = *(const float4*)(wr + 8);                           \
            const float4 w3 = *(const float4*)(wr + 12);                          \
            float t = a16[j];                                                     \
            t = fmaf(kr[0],  w0.x, t); t = fmaf(kr[1],  w0.y, t);                 \
            t = fmaf(kr[2],  w0.z, t); t = fmaf(kr[3],  w0.w, t);                 \
            t = fmaf(kr[4],  w1.x, t); t = fmaf(kr[5],  w1.y, t);                 \
            t = fmaf(kr[6],  w1.z, t); t = fmaf(kr[7],  w1.w, t);                 \
            t = fmaf(kr[8],  w2.x, t); t = fmaf(kr[9],  w2.y, t);                 \
            t = fmaf(kr[10], w2.z, t); t = fmaf(kr[11], w2.w, t);                 \
            t = fmaf(kr[12], w3.x, t); t = fmaf(kr[13], w3.y, t);                 \
            t = fmaf(kr[14], w3.z, t); t = fmaf(kr[15], w3.w, t);                 \
            a16[j] = t;                                                           \
        }                                                                         \
    }

// ---------------------------------------------------------------------------
// K1a: feature map over K. K2's proven output structure: feature -> LDS
// (conflict-free scalar writes), then fully-coalesced full-line global stores.
//   kf_ws[pair][d][n] (written via LDS transpose)
//   ks_part[chunk][pair][d] = sum over this block's 64 tokens
// ---------------------------------------------------------------------------
__global__ __launch_bounds__(256, 4) void k_feat_k(const float* __restrict__ kin,
                                                   const float* __restrict__ fm_w,
                                                   const float* __restrict__ fm_b,
                                                   float* __restrict__ kf_ws,
                                                   float* __restrict__ ks_part)
{
    __shared__ float kfT[64][FPAD];   // [d_f][n]

    const int tid  = threadIdx.x;
    const int lane = tid & 63;
    const int wv   = tid >> 6;

    const int pair  = blockIdx.x >> 6;
    const int chunk = blockIdx.x & 63;
    const int n0    = chunk * 64;
    const int bb = pair >> 3, hh = pair & 7;
    const float* kb = kin + (size_t)(bb * CDIM + hh * HD) * NTOK;

    const int fn  = lane;
    const int e0f = wv * 16;

    float a16[16];
    #pragma unroll
    for (int j = 0; j < 16; ++j) a16[j] = fm_b[e0f + j];
    #pragma unroll
    for (int db = 0; db < 4; ++db) FEAT_DB_STEP(kb)

    #pragma unroll
    for (int j = 0; j < 16; ++j) {
        a16[j] = elu_eps(a16[j]);
        kfT[e0f + j][fn] = a16[j];    // conflict-free: 64 lanes, consecutive cols
    }

    // ksum chunk-partials (shuffle reduce; deterministic, no atomics)
    #pragma unroll
    for (int j = 0; j < 16; ++j) {
        float v = a16[j];
        v += __shfl_xor(v, 1, 64);
        v += __shfl_xor(v, 2, 64);
        v += __shfl_xor(v, 4, 64);
        v += __shfl_xor(v, 8, 64);
        v += __shfl_xor(v, 16, 64);
        v += __shfl_xor(v, 32, 64);
        if (lane == 0)
            ks_part[((size_t)chunk * NPAIRS + pair) * HD + e0f + j] = v;
    }

    __syncthreads();

    // coalesced write-out: 16-lane groups write contiguous 256B runs per row
    float* kfb = kf_ws + (size_t)pair * HD * NTOK;
    const int dr = tid >> 4;          // row 0..15 (+16i)
    const int nc = (tid & 15) * 4;    // col quad
    #pragma unroll
    for (int i = 0; i < 4; ++i) {
        const int d = dr + 16 * i;
        *(float4*)(kfb + (size_t)d * NTOK + n0 + nc) = *(const float4*)&kfT[d][nc];
    }
}

// ---------------------------------------------------------------------------
// K1b: pure GEMM  kv_part[split][pair][d][e] = sum_{n in split} kf[n][d] v[n][e]
// (verbatim round 9 — no spills, works)
// ---------------------------------------------------------------------------
__global__ __launch_bounds__(256, 3) void k_kv(const float* __restrict__ vin,
                                               const float* __restrict__ kf_ws,
                                               float* __restrict__ kv_part)
{
    __shared__ float kf_l[64][PAD];   // [n][d]
    __shared__ float vtT[64][PAD];    // [n][e]

    const int tid  = threadIdx.x;
    const int lane = tid & 63;
    const int wv   = tid >> 6;

    const int pair  = blockIdx.x >> 4;
    const int split = blockIdx.x & (K1B_SPLIT - 1);
    const int bb = pair >> 3, hh = pair & 7;
    const float* vb  = vin + (size_t)(bb * CDIM + hh * HD) * NTOK;
    const float* kfb = kf_ws + (size_t)pair * HD * NTOK;

    const int dq = (tid >> 4) * 4;    // staging row quad (d or e)
    const int nq = (tid & 15) * 4;    // staging n quad
    const int d0 = (lane >> 3) * 8;   // GEMM tile rows
    const int e0 = (lane & 7) * 8;    // GEMM tile cols

    float acc[8][8];
    #pragma unroll
    for (int i = 0; i < 8; ++i)
        #pragma unroll
        for (int j = 0; j < 8; ++j) acc[i][j] = 0.f;

    #pragma unroll 1
    for (int c = 0; c < 4; ++c) {
        const int n0 = split * 256 + c * 64;
        __syncthreads();   // previous chunk's GEMM reads done

        // stage kf chunk: rows d=dq+r, 4x4 transpose -> kf_l[n][d]
        {
            float4 x0 = *(const float4*)(kfb + (size_t)(dq + 0) * NTOK + n0 + nq);
            float4 x1 = *(const float4*)(kfb + (size_t)(dq + 1) * NTOK + n0 + nq);
            float4 x2 = *(const float4*)(kfb + (size_t)(dq + 2) * NTOK + n0 + nq);
            float4 x3 = *(const float4*)(kfb + (size_t)(dq + 3) * NTOK + n0 + nq);
            *(float4*)&kf_l[nq + 0][dq] = make_float4(x0.x, x1.x, x2.x, x3.x);
            *(float4*)&kf_l[nq + 1][dq] = make_float4(x0.y, x1.y, x2.y, x3.y);
            *(float4*)&kf_l[nq + 2][dq] = make_float4(x0.z, x1.z, x2.z, x3.z);
            *(float4*)&kf_l[nq + 3][dq] = make_float4(x0.w, x1.w, x2.w, x3.w);
        }
        // stage V chunk: rows e=dq+r, 4x4 transpose -> vtT[n][e]
        {
            float4 x0 = *(const float4*)(vb + (size_t)(dq + 0) * NTOK + n0 + nq);
            float4 x1 = *(const float4*)(vb + (size_t)(dq + 1) * NTOK + n0 + nq);
            float4 x2 = *(const float4*)(vb + (size_t)(dq + 2) * NTOK + n0 + nq);
            float4 x3 = *(const float4*)(vb + (size_t)(dq + 3) * NTOK + n0 + nq);
            *(float4*)&vtT[nq + 0][dq] = make_float4(x0.x, x1.x, x2.x, x3.x);
            *(float4*)&vtT[nq + 1][dq] = make_float4(x0.y, x1.y, x2.y, x3.y);
            *(float4*)&vtT[nq + 2][dq] = make_float4(x0.z, x1.z, x2.z, x3.z);
            *(float4*)&vtT[nq + 3][dq] = make_float4(x0.w, x1.w, x2.w, x3.w);
        }
        __syncthreads();

        // broadcast 8x8 GEMM: wave wv owns tokens [16wv, 16wv+16)
        #pragma unroll 4
        for (int tt = 0; tt < 16; ++tt) {
            const int n = 16 * wv + tt;   // wave-uniform -> broadcast LDS reads
            const float4 a0_ = *(const float4*)&kf_l[n][d0];
            const float4 a1_ = *(const float4*)&kf_l[n][d0 + 4];
            const float4 b0_ = *(const float4*)&vtT[n][e0];
            const float4 b1_ = *(const float4*)&vtT[n][e0 + 4];
            const float av[8] = {a0_.x, a0_.y, a0_.z, a0_.w, a1_.x, a1_.y, a1_.z, a1_.w};
            const float bv[8] = {b0_.x, b0_.y, b0_.z, b0_.w, b1_.x, b1_.y, b1_.z, b1_.w};
            #pragma unroll
            for (int i = 0; i < 8; ++i)
                #pragma unroll
                for (int j = 0; j < 8; ++j)
                    acc[i][j] = fmaf(av[i], bv[j], acc[i][j]);
        }
    }

    // cross-wave reduce (reuse kf_l as Red), then store partial
    __syncthreads();
    for (int w = 0; w < 4; ++w) {
        if (wv == w) {
            #pragma unroll
            for (int i = 0; i < 8; ++i) {
                if (w == 0) {
                    *(float4*)&kf_l[d0 + i][e0]     = make_float4(acc[i][0], acc[i][1], acc[i][2], acc[i][3]);
                    *(float4*)&kf_l[d0 + i][e0 + 4] = make_float4(acc[i][4], acc[i][5], acc[i][6], acc[i][7]);
                } else {
                    float4 r0 = *(const float4*)&kf_l[d0 + i][e0];
                    float4 r1 = *(const float4*)&kf_l[d0 + i][e0 + 4];
                    r0.x += acc[i][0]; r0.y += acc[i][1]; r0.z += acc[i][2]; r0.w += acc[i][3];
                    r1.x += acc[i][4]; r1.y += acc[i][5]; r1.z += acc[i][6]; r1.w += acc[i][7];
                    *(float4*)&kf_l[d0 + i][e0]     = r0;
                    *(float4*)&kf_l[d0 + i][e0 + 4] = r1;
                }
            }
        }
        __syncthreads();
    }
    {
        float* kvp = kv_part + ((size_t)split * NPAIRS + pair) * (HD * HD);
        const int r0 = (tid >> 4) * 4;
        const int c0 = (tid & 15) * 4;
        #pragma unroll
        for (int i = 0; i < 4; ++i)
            *(float4*)(kvp + (size_t)(r0 + i) * HD + c0) = *(const float4*)&kf_l[r0 + i][c0];
    }
}

// ---------------------------------------------------------------------------
// K1c: deterministic fixed-order fp64 reduce of partials.
// ---------------------------------------------------------------------------
__global__ __launch_bounds__(256) void k_reduce(const float* __restrict__ kv_part,
                                                const float* __restrict__ ks_part,
                                                float* __restrict__ kv_g,
                                                float* __restrict__ ksum_g)
{
    const int pair = blockIdx.x >> 2;
    const int qtr  = blockIdx.x & 3;
    const int tid  = threadIdx.x;

    #pragma unroll
    for (int i = 0; i < 4; ++i) {
        const int idx = qtr * 1024 + i * 256 + tid;
        double s = 0.0;
        for (int sp = 0; sp < K1B_SPLIT; ++sp)
            s += (double)kv_part[((size_t)sp * NPAIRS + pair) * (HD * HD) + idx];
        kv_g[(size_t)pair * (HD * HD) + idx] = (float)(s * ATT_SCALE);
    }
    if (qtr == 0 && tid < HD) {
        double s = 0.0;
        for (int c = 0; c < 64; ++c)
            s += (double)ks_part[((size_t)c * NPAIRS + pair) * HD + tid];
        ksum_g[(size_t)pair * HD + tid] = (float)s;
    }
}

// ---------------------------------------------------------------------------
// K2: out[n][e] = (qf[n]·kv[:,e]) / (qf[n]·ksum + eps), fp32 (verbatim r5/r9)
// ---------------------------------------------------------------------------
__global__ __launch_bounds__(256, 3) void k_qout(const float* __restrict__ qin,
                                                 const float* __restrict__ fm_w,
                                                 const float* __restrict__ fm_b,
                                                 const float* __restrict__ kv_g,
                                                 const float* __restrict__ ksum_g,
                                                 float* __restrict__ outp)
{
    __shared__ float kvs[64][PAD];   // [d][e]
    __shared__ float qfT[64][PAD];   // [d_f][n]; reused as RedT after out phase
    __shared__ float nred[4][64];
    __shared__ float norm_lds[64];

    const int tid  = threadIdx.x;
    const int lane = tid & 63;
    const int wv   = tid >> 6;

    const int pair  = blockIdx.x >> 6;
    const int chunk = blockIdx.x & 63;
    const int n0    = chunk * 64;
    const int bb = pair >> 3, hh = pair & 7;
    const float* qb = qin + (size_t)(bb * CDIM + hh * HD) * NTOK;

    // ---- stage kv tile ----
    {
        const float* kvg = kv_g + (size_t)pair * (HD * HD);
        const int d  = tid >> 2;
        const int eb = (tid & 3) * 16;
        #pragma unroll
        for (int i = 0; i < 4; ++i)
            *(float4*)&kvs[d][eb + 4 * i] = *(const float4*)(kvg + (size_t)d * 64 + eb + 4 * i);
    }

    const int fn  = lane;
    const int e0f = wv * 16;
    float bias[16], ksr[16];
    #pragma unroll
    for (int j = 0; j < 16; ++j) {
        bias[j] = fm_b[e0f + j];
        ksr[j]  = ksum_g[(size_t)pair * HD + e0f + j];
    }

    // ---- feature map (Q direct from global) -> qfT + normalizer partial ----
    {
        float a16[16];
        #pragma unroll
        for (int j = 0; j < 16; ++j) a16[j] = bias[j];
        #pragma unroll
        for (int db = 0; db < 4; ++db) FEAT_DB_STEP(qb)
        float np = 0.f;
        #pragma unroll
        for (int j = 0; j < 16; ++j) {
            const float v = elu_eps(a16[j]);
            np = fmaf(v, ksr[j], np);
            qfT[e0f + j][fn] = v;
        }
        nred[wv][fn] = np;
    }
    __syncthreads();
    if (tid < 64)
        norm_lds[tid] = nred[0][tid] + nred[1][tid] + nred[2][tid] + nred[3][tid] + EPS_F;
    __syncthreads();

    // ---- out GEMM (transposed acc): wave wv owns d in [16wv, 16wv+16) ----
    const int ea0 = (lane >> 3) * 8;
    const int na0 = (lane & 7) * 8;
    float acc[8][8];
    #pragma unroll
    for (int i = 0; i < 8; ++i)
        #pragma unroll
        for (int j = 0; j < 8; ++j) acc[i][j] = 0.f;
    #pragma unroll
    for (int dd = 0; dd < 16; ++dd) {
        const int d = 16 * wv + dd;   // wave-uniform
        const float4 a0_ = *(const float4*)&kvs[d][ea0];
        const float4 a1_ = *(const float4*)&kvs[d][ea0 + 4];
        const float4 b0_ = *(const float4*)&qfT[d][na0];
        const float4 b1_ = *(const float4*)&qfT[d][na0 + 4];
        const float av[8] = {a0_.x, a0_.y, a0_.z, a0_.w, a1_.x, a1_.y, a1_.z, a1_.w};
        const float bv[8] = {b0_.x, b0_.y, b0_.z, b0_.w, b1_.x, b1_.y, b1_.z, b1_.w};
        #pragma unroll
        for (int i = 0; i < 8; ++i)
            #pragma unroll
            for (int j = 0; j < 8; ++j)
                acc[i][j] = fmaf(av[i], bv[j], acc[i][j]);
    }
    __syncthreads();   // all qfT reads done; safe to overwrite as RedT

    for (int w = 0; w < 4; ++w) {
        if (wv == w) {
            #pragma unroll
            for (int i = 0; i < 8; ++i) {
                if (w == 0) {
                    *(float4*)&qfT[ea0 + i][na0]     = make_float4(acc[i][0], acc[i][1], acc[i][2], acc[i][3]);
                    *(float4*)&qfT[ea0 + i][na0 + 4] = make_float4(acc[i][4], acc[i][5], acc[i][6], acc[i][7]);
                } else {
                    float4 r0 = *(const float4*)&qfT[ea0 + i][na0];
                    float4 r1 = *(const float4*)&qfT[ea0 + i][na0 + 4];
                    r0.x += acc[i][0]; r0.y += acc[i][1]; r0.z += acc[i][2]; r0.w += acc[i][3];
                    r1.x += acc[i][4]; r1.y += acc[i][5]; r1.z += acc[i][6]; r1.w += acc[i][7];
                    *(float4*)&qfT[ea0 + i][na0]     = r0;
                    *(float4*)&qfT[ea0 + i][na0 + 4] = r1;
                }
            }
        }
        __syncthreads();
    }

    // ---- epilogue: divide by normalizer, coalesced store ----
    {
        const int er0 = (tid >> 4) * 4;   // e rows
        const int nc0 = (tid & 15) * 4;   // n cols
        float rn[4];
        #pragma unroll
        for (int j = 0; j < 4; ++j) rn[j] = 1.f / norm_lds[nc0 + j];
        float* ob = outp + (size_t)(bb * CDIM + hh * HD) * NTOK + n0;
        #pragma unroll
        for (int i = 0; i < 4; ++i) {
            float4 vv = *(const float4*)&qfT[er0 + i][nc0];
            vv.x *= rn[0]; vv.y *= rn[1]; vv.z *= rn[2]; vv.w *= rn[3];
            *(float4*)(ob + (size_t)(er0 + i) * NTOK + nc0) = vv;
        }
    }
}

// ---------------------------------------------------------------------------
// K3: in-place LayerNorm over C, 16 tokens/block, two-pass variance
// ---------------------------------------------------------------------------
__global__ __launch_bounds__(256) void k_layernorm(float* __restrict__ io,
                                                   const float* __restrict__ ln_w,
                                                   const float* __restrict__ ln_b)
{
    __shared__ float xs[512][17];
    __shared__ float mu_s[16];
    __shared__ float rs_s[16];

    const int tid = threadIdx.x;
    const int bb = blockIdx.x >> 8;
    const int chunk = blockIdx.x & 255;
    const int n0 = chunk * 16;
    float* base = io + (size_t)bb * CDIM * NTOK + n0;

    #pragma unroll
    for (int i = 0; i < 8; ++i) {
        const int idx = tid + i * 256;
        const int c = idx >> 2;
        const int f4 = (idx & 3) * 4;
        const float4 vx = *(const float4*)(base + (size_t)c * NTOK + f4);
        xs[c][f4 + 0] = vx.x; xs[c][f4 + 1] = vx.y;
        xs[c][f4 + 2] = vx.z; xs[c][f4 + 3] = vx.w;
    }
    __syncthreads();

    const int n = tid >> 4;
    const int p = tid & 15;
    float s = 0.f;
    #pragma unroll 8
    for (int ci = 0; ci < 32; ++ci) {
        const int c = p * 32 + ((ci + 2 * p) & 31);
        s += xs[c][n];
    }
    s += __shfl_xor(s, 1, 64);
    s += __shfl_xor(s, 2, 64);
    s += __shfl_xor(s, 4, 64);
    s += __shfl_xor(s, 8, 64);
    if (p == 0) mu_s[n] = s * (1.f / 512.f);
    __syncthreads();
    const float mu = mu_s[n];
    float s2 = 0.f;
    #pragma unroll 8
    for (int ci = 0; ci < 32; ++ci) {
        const int c = p * 32 + ((ci + 2 * p) & 31);
        const float x = xs[c][n] - mu;
        s2 = fmaf(x, x, s2);
    }
    s2 += __shfl_xor(s2, 1, 64);
    s2 += __shfl_xor(s2, 2, 64);
    s2 += __shfl_xor(s2, 4, 64);
    s2 += __shfl_xor(s2, 8, 64);
    if (p == 0) rs_s[n] = rsqrtf(s2 * (1.f / 512.f) + EPS_LN);
    __syncthreads();

    #pragma unroll
    for (int i = 0; i < 8; ++i) {
        const int idx = tid + i * 256;
        const int c = idx >> 2;
        const int f4 = (idx & 3) * 4;
        const float w = ln_w[c];
        const float b2 = ln_b[c];
        float4 ov;
        ov.x = (xs[c][f4 + 0] - mu_s[f4 + 0]) * rs_s[f4 + 0] * w + b2;
        ov.y = (xs[c][f4 + 1] - mu_s[f4 + 1]) * rs_s[f4 + 1] * w + b2;
        ov.z = (xs[c][f4 + 2] - mu_s[f4 + 2]) * rs_s[f4 + 2] * w + b2;
        ov.w = (xs[c][f4 + 3] - mu_s[f4 + 3]) * rs_s[f4 + 3] * w + b2;
        *(float4*)(base + (size_t)c * NTOK + f4) = ov;
    }
}

// ---------------------------------------------------------------------------
extern "C" void kernel_launch(void* const* d_in, const int* in_sizes, int n_in,
                              void* d_out, int out_size, void* d_ws, size_t ws_size,
                              hipStream_t stream) {
    (void)in_sizes; (void)n_in; (void)out_size; (void)ws_size;
    const float* q    = (const float*)d_in[0];
    const float* k    = (const float*)d_in[1];
    const float* v    = (const float*)d_in[2];
    const float* fm_w = (const float*)d_in[3];
    const float* fm_b = (const float*)d_in[4];
    const float* ln_w = (const float*)d_in[5];
    const float* ln_b = (const float*)d_in[6];
    float* out = (float*)d_out;

    // ws layout (all regions fully written before read; no memset needed):
    float* kf_ws   = (float*)d_ws;                                   // 64*64*4096   = 16.78M floats
    float* kv_part = kf_ws   + (size_t)NPAIRS * HD * NTOK;           // 16*64*64*64  =  4.19M
    float* ks_part = kv_part + (size_t)K1B_SPLIT * NPAIRS * HD * HD; // 64*64*64     =  0.26M
    float* kv_g    = ks_part + (size_t)64 * NPAIRS * HD;             // 64*64*64     =  0.26M
    float* ksum_g  = kv_g    + (size_t)NPAIRS * HD * HD;             // 64*64

    k_feat_k<<<NPAIRS * 64, 256, 0, stream>>>(k, fm_w, fm_b, kf_ws, ks_part);
    k_kv<<<NPAIRS * K1B_SPLIT, 256, 0, stream>>>(v, kf_ws, kv_part);
    k_reduce<<<NPAIRS * 4, 256, 0, stream>>>(kv_part, ks_part, kv_g, ksum_g);
    k_qout<<<NPAIRS * (NTOK / 64), 256, 0, stream>>>(q, fm_w, fm_b, kv_g, ksum_g, out);
    k_layernorm<<<8 * (NTOK / 16), 256, 0, stream>>>(out, ln_w, ln_b);
}